// Round 4
// baseline (1279.243 us; speedup 1.0000x reference)
//
#include <hip/hip_runtime.h>
#include <hip/hip_bf16.h>

#define NTOK 32768
#define KEMB 4096
#define DDIM 256
#define DECAYF 0.99f
#define EPSF 1e-5f
#define KSPLIT 512   // 2-term fp16 split: [Xh|Xl] . [Ch|Ch]

// ---------------- workspace layout (BYTE offsets) ----------------
#define B_AHAT  0ull          // 32768*512 f16 = 33554432 B  [Xh|Xl]
#define B_BHAT  33554432ull   // 4096*512 f16  = 4194304 B   [Ch|Ch]
#define B_PART  37748736ull   // 32768*64 float4 = 33554432 B per-64col-chunk (b1,b2,idx)
#define B_CE    71303168ull   // 4096 f32
#define B_CNT   71319552ull   // 4096 f32
#define B_CSP   71335936ull   // 4096 f32
#define B_NPTR  71352320ull   // f32 n
#define B_FLAGC 71352324ull   // int flag count
#define B_TIDX  71352384ull   // 32768 int
#define B_FLIST 71483456ull   // 32768 int
#define B_DW    71614528ull   // 4096*256 f32 = 4194304 B
// total ~75.8 MB

// ---------------- output layout (float offsets) ----------------
#define OFF_Q  0ull                 // quantized  [32768,256]
#define OFF_E  8388608ull           // encodings  [32768,4096]
#define OFF_CB 142606336ull         // new_codebook [4096,256]
#define OFF_W  143654912ull         // new_ema_w    [4096,256]
#define OFF_CS 144703488ull         // cs [4096]

typedef __attribute__((ext_vector_type(8))) _Float16 f16x8;
typedef __attribute__((ext_vector_type(4))) float f32x4;

// ---- split fp32 -> (hi, lo) fp16, Ahat = [Xh | Xl] along K ----
__global__ __launch_bounds__(256) void splitA_kernel(const float* __restrict__ x,
                                                     _Float16* __restrict__ Ahat) {
    int gid = blockIdx.x * 256 + threadIdx.x;   // 0 .. 32768*32-1
    int i = gid >> 5;
    int c = gid & 31;                           // 8-elem chunk
    const float* xp = x + (size_t)i * DDIM + c * 8;
    f16x8 hi, lo;
    #pragma unroll
    for (int t = 0; t < 8; ++t) {
        float v = xp[t];
        _Float16 h = (_Float16)v;
        _Float16 l = (_Float16)(v - (float)h);
        hi[t] = h;
        lo[t] = l;
    }
    _Float16* row = Ahat + (size_t)i * KSPLIT + c * 8;
    *(f16x8*)(row)       = hi;
    *(f16x8*)(row + 256) = lo;
}

// ---- Bhat = [Ch | Ch] along K; also emits ce[j] = ||c_j||^2 (fp32) ----
__global__ __launch_bounds__(256) void splitB_kernel(const float* __restrict__ cb,
                                                     _Float16* __restrict__ Bhat,
                                                     float* __restrict__ ce) {
    int gid = blockIdx.x * 256 + threadIdx.x;   // 0 .. 4096*32-1
    int j = gid >> 5;
    int c = gid & 31;
    const float* cp = cb + (size_t)j * DDIM + c * 8;
    f16x8 hi;
    float nrm = 0.0f;
    #pragma unroll
    for (int t = 0; t < 8; ++t) {
        float v = cp[t];
        nrm = fmaf(v, v, nrm);
        hi[t] = (_Float16)v;
    }
    _Float16* row = Bhat + (size_t)j * KSPLIT + c * 8;
    *(f16x8*)(row)       = hi;
    *(f16x8*)(row + 256) = hi;
    // reduce ||c_j||^2 across the 32 threads of row j (32-lane subgroup)
    #pragma unroll
    for (int m = 16; m > 0; m >>= 1) nrm += __shfl_xor(nrm, m, 32);
    if (c == 0) ce[j] = nrm;
}

// ---- fp16 MFMA GEMM (M=32768, N=4096, K=512) with fused per-row argmin.
// 128x128 tile, BK=64, global_load_lds width-16, XOR-swizzled chunk staging
// (LDS[row][c] holds global chunk c^(row&7)) -> conflict-free ds_read_b128.
__global__ __launch_bounds__(256) void gemm_argmin_kernel(
        const _Float16* __restrict__ Ahat,
        const _Float16* __restrict__ Bhat,
        const float* __restrict__ ceg,
        float4* __restrict__ part) {
    __shared__ _Float16 As[128 * 64];   // 16 KB
    __shared__ _Float16 Bs[128 * 64];   // 16 KB
    const int tid  = threadIdx.x;
    const int lane = tid & 63;
    const int wave = tid >> 6;
    const int wm = wave >> 1, wn = wave & 1;  // 2x2 wave grid, 64x64 per wave
    const int mb = blockIdx.x, nb = blockIdx.y;
    const int col = lane & 15, q = lane >> 4;
    const int cswz = q ^ (col & 7);           // reader chunk swizzle base

    // staging: thread t handles (row = n*32 + t/8, chunk = t%8), fetches the
    // XOR-swizzled global chunk so LDS stays lane-contiguous for the DMA.
    const int srow = tid >> 3;
    const int sswz = (tid & 7) ^ (srow & 7);
    const _Float16* ag = Ahat + (size_t)(mb * 128 + srow) * KSPLIT + sswz * 8;
    const _Float16* bg = Bhat + (size_t)(nb * 128 + srow) * KSPLIT + sswz * 8;

    f32x4 zero = {0.f, 0.f, 0.f, 0.f};
    f32x4 acc[4][4];
    #pragma unroll
    for (int i = 0; i < 4; ++i)
        #pragma unroll
        for (int j = 0; j < 4; ++j) acc[i][j] = zero;

    for (int kt = 0; kt < KSPLIT / 64; ++kt) {
        __syncthreads();
        #pragma unroll
        for (int n = 0; n < 4; ++n) {
            __builtin_amdgcn_global_load_lds(
                (const __attribute__((address_space(1))) void*)(ag + (size_t)n * 32 * KSPLIT + kt * 64),
                (__attribute__((address_space(3))) void*)(As + n * 2048 + tid * 8), 16, 0, 0);
            __builtin_amdgcn_global_load_lds(
                (const __attribute__((address_space(1))) void*)(bg + (size_t)n * 32 * KSPLIT + kt * 64),
                (__attribute__((address_space(3))) void*)(Bs + n * 2048 + tid * 8), 16, 0, 0);
        }
        __syncthreads();

        const f16x8* Av = (const f16x8*)As;
        const f16x8* Bv = (const f16x8*)Bs;
        #pragma unroll
        for (int ks = 0; ks < 2; ++ks) {
            f16x8 a[4], b[4];
            #pragma unroll
            for (int i = 0; i < 4; ++i)
                a[i] = Av[(wm * 64 + i * 16 + col) * 8 + (cswz ^ (ks * 4))];
            #pragma unroll
            for (int j = 0; j < 4; ++j)
                b[j] = Bv[(wn * 64 + j * 16 + col) * 8 + (cswz ^ (ks * 4))];
            #pragma unroll
            for (int i = 0; i < 4; ++i)
                #pragma unroll
                for (int j = 0; j < 4; ++j)
                    acc[i][j] = __builtin_amdgcn_mfma_f32_16x16x32_f16(a[i], b[j], acc[i][j], 0, 0, 0);
        }
    }

    // epilogue: s = ||c||^2 - 2*dot. C/D layout: col = lane&15, row = q*4+reg.
    float ce_j[4];
    #pragma unroll
    for (int j = 0; j < 4; ++j) ce_j[j] = ceg[nb * 128 + wn * 64 + j * 16 + col];

    #pragma unroll
    for (int i = 0; i < 4; ++i) {
        #pragma unroll
        for (int r = 0; r < 4; ++r) {
            float b1 = 3.4e38f, b2 = 3.4e38f;
            int i1 = 0x7fffffff;
            #pragma unroll
            for (int j = 0; j < 4; ++j) {
                float s = ce_j[j] - 2.0f * acc[i][j][r];
                int n = nb * 128 + wn * 64 + j * 16 + col;
                if (s < b1) { b2 = b1; b1 = s; i1 = n; }
                else if (s < b2) { b2 = s; }
            }
            #pragma unroll
            for (int m = 1; m < 16; m <<= 1) {
                float ob1 = __shfl_xor(b1, m, 16);
                float ob2 = __shfl_xor(b2, m, 16);
                int   oi  = __shfl_xor(i1, m, 16);
                bool take = (ob1 < b1) || (ob1 == b1 && oi < i1);
                float nb2 = take ? fminf(b1, ob2) : fminf(b2, ob1);
                if (take) { b1 = ob1; i1 = oi; }
                b2 = nb2;
            }
            if (col == i * 4 + r) {   // unique writer lane per (q,i,r)
                int mrow = mb * 128 + wm * 64 + i * 16 + q * 4 + r;
                float4 p;
                p.x = b1; p.y = b2; p.z = __int_as_float(i1); p.w = 0.0f;
                part[(size_t)mrow * 64 + nb * 2 + wn] = p;
            }
        }
    }
}

// ---- merge 64 column-chunk partials per row; flag near-ties ----
__global__ __launch_bounds__(256) void argmin_reduce_kernel(
        const float4* __restrict__ part,
        int* __restrict__ tokIdx,
        int* __restrict__ flist,
        int* __restrict__ flagCount) {
    int row = blockIdx.x * 4 + (threadIdx.x >> 6);
    int lane = threadIdx.x & 63;
    float4 p = part[(size_t)row * 64 + lane];
    float b1 = p.x, b2 = p.y;
    int i1 = __float_as_int(p.z);
    #pragma unroll
    for (int m = 1; m < 64; m <<= 1) {
        float ob1 = __shfl_xor(b1, m);
        float ob2 = __shfl_xor(b2, m);
        int   oi  = __shfl_xor(i1, m);
        bool take = (ob1 < b1) || (ob1 == b1 && oi < i1);
        float nb2 = take ? fminf(b1, ob2) : fminf(b2, ob1);
        if (take) { b1 = ob1; i1 = oi; }
        b2 = nb2;
    }
    if (lane == 0) {
        tokIdx[row] = i1;
        if (b2 - b1 < 0.125f) {   // near-tie vs fp16-split error (~3e-3): refine
            int slot = atomicAdd(flagCount, 1);
            flist[slot] = row;
        }
    }
}

// ---- fp64 exact re-resolution of flagged tokens ----
__global__ __launch_bounds__(256) void refine_kernel(const float* __restrict__ xg,
                                                     const float* __restrict__ cb,
                                                     int* __restrict__ tokIdx,
                                                     const int* __restrict__ flagList,
                                                     const int* __restrict__ flagCount) {
    __shared__ double xs[256];
    __shared__ double rb[256];
    __shared__ int    ri[256];
    int nf = *flagCount;
    for (int f = blockIdx.x; f < nf; f += gridDim.x) {
        int tok = flagList[f];
        __syncthreads();
        xs[threadIdx.x] = (double)xg[(size_t)tok * DDIM + threadIdx.x];
        __syncthreads();
        double best = 1e300;
        int bi = 0x7fffffff;
        for (int kk = 0; kk < KEMB / 256; ++kk) {
            int k = kk * 256 + threadIdx.x;
            const float* e = cb + (size_t)k * DDIM;
            double s = 0.0;
            for (int d4 = 0; d4 < DDIM / 4; ++d4) {
                float4 e4 = *(const float4*)(e + d4 * 4);
                double e0 = (double)e4.x, e1 = (double)e4.y;
                double e2 = (double)e4.z, e3 = (double)e4.w;
                s += e0 * (e0 - 2.0 * xs[d4 * 4 + 0]) + e1 * (e1 - 2.0 * xs[d4 * 4 + 1])
                   + e2 * (e2 - 2.0 * xs[d4 * 4 + 2]) + e3 * (e3 - 2.0 * xs[d4 * 4 + 3]);
            }
            if (s < best) { best = s; bi = k; }
        }
        rb[threadIdx.x] = best;
        ri[threadIdx.x] = bi;
        __syncthreads();
        if (threadIdx.x == 0) {
            double b = rb[0]; int i1 = ri[0];
            for (int c = 1; c < 256; ++c) {
                if (rb[c] < b || (rb[c] == b && ri[c] < i1)) { b = rb[c]; i1 = ri[c]; }
            }
            tokIdx[tok] = i1;
        }
        __syncthreads();
    }
}

// ---- per-token scatter: FULL one-hot row (replaces 512MB memset pass),
// quantized row, dw/counts atomics. One block per token, 256 threads. ----
__global__ __launch_bounds__(256) void scatter_kernel(const float* __restrict__ xg,
                                                      const float* __restrict__ cb,
                                                      const int* __restrict__ tokIdx,
                                                      float* __restrict__ quant,
                                                      float* __restrict__ enc,
                                                      float* __restrict__ dw,
                                                      float* __restrict__ counts) {
    int tok = blockIdx.x;
    int tid = threadIdx.x;
    int k = tokIdx[tok];
    // one-hot row: 4096 floats = 1024 float4, 4 per thread (streaming stores)
    float4* er = (float4*)(enc + (size_t)tok * KEMB);
    int kf4 = k >> 2, kc = k & 3;
    #pragma unroll
    for (int v = 0; v < 4; ++v) {
        int f4 = v * 256 + tid;
        float4 val = {0.f, 0.f, 0.f, 0.f};
        if (f4 == kf4) ((float*)&val)[kc] = 1.0f;
        er[f4] = val;
    }
    if (tid < 64) {
        float4 e = *(const float4*)(cb + (size_t)k * DDIM + tid * 4);
        *(float4*)(quant + (size_t)tok * DDIM + tid * 4) = e;
        float4 xv = *(const float4*)(xg + (size_t)tok * DDIM + tid * 4);
        float* dwr = dw + (size_t)k * DDIM + tid * 4;
        atomicAdd(dwr + 0, xv.x);
        atomicAdd(dwr + 1, xv.y);
        atomicAdd(dwr + 2, xv.z);
        atomicAdd(dwr + 3, xv.w);
    }
    if (tid == 128) atomicAdd(counts + k, 1.0f);
}

// ---- cs_pre = ema_cs*decay + (1-decay)*counts ; n = sum(cs_pre) ----
__global__ __launch_bounds__(256) void cs_kernel(const float* __restrict__ ema_cs,
                                                 const float* __restrict__ counts,
                                                 float* __restrict__ cs_pre,
                                                 float* __restrict__ nptr) {
    int k = blockIdx.x * 256 + threadIdx.x;
    float c = ema_cs[k] * DECAYF + (1.0f - DECAYF) * counts[k];
    cs_pre[k] = c;
    float s = c;
    #pragma unroll
    for (int o = 32; o > 0; o >>= 1) s += __shfl_down(s, o);
    __shared__ float red[4];
    int lane = threadIdx.x & 63, w = threadIdx.x >> 6;
    if (lane == 0) red[w] = s;
    __syncthreads();
    if (threadIdx.x == 0) atomicAdd(nptr, red[0] + red[1] + red[2] + red[3]);
}

// ---- epilogue: new_ema_w, laplace-smoothed cs, new_codebook ----
__global__ __launch_bounds__(256) void epi_kernel(const float* __restrict__ ema_w,
                                                  const float* __restrict__ dw,
                                                  const float* __restrict__ cs_pre,
                                                  const float* __restrict__ nptr,
                                                  float* __restrict__ new_cb,
                                                  float* __restrict__ new_w,
                                                  float* __restrict__ cs_out) {
    int gid = blockIdx.x * 256 + threadIdx.x;   // 0 .. 1048575
    int k = gid >> 8, d = gid & 255;
    float n = *nptr;
    float csp = cs_pre[k];
    float cs = (csp + EPSF) / (n + (float)KEMB * EPSF) * n;
    float w = ema_w[gid] * DECAYF + (1.0f - DECAYF) * dw[gid];
    new_w[gid] = w;
    new_cb[gid] = w / cs;
    if (d == 0) cs_out[k] = cs;
}

extern "C" void kernel_launch(void* const* d_in, const int* in_sizes, int n_in,
                              void* d_out, int out_size, void* d_ws, size_t ws_size,
                              hipStream_t stream) {
    const float* xg     = (const float*)d_in[0];   // [32768,256]
    const float* cbg    = (const float*)d_in[1];   // [4096,256]
    const float* ema_w  = (const float*)d_in[2];   // [4096,256]
    const float* ema_cs = (const float*)d_in[3];   // [4096]

    float* out = (float*)d_out;
    unsigned char* wsb = (unsigned char*)d_ws;

    float* quant  = out + OFF_Q;
    float* enc    = out + OFF_E;
    float* new_cb = out + OFF_CB;
    float* new_w  = out + OFF_W;
    float* cs_out = out + OFF_CS;

    _Float16* Ahat = (_Float16*)(wsb + B_AHAT);
    _Float16* Bhat = (_Float16*)(wsb + B_BHAT);
    float4* part   = (float4*)(wsb + B_PART);
    float* ce      = (float*)(wsb + B_CE);
    float* counts  = (float*)(wsb + B_CNT);
    float* cs_pre  = (float*)(wsb + B_CSP);
    float* nptr    = (float*)(wsb + B_NPTR);
    int*   flagCnt = (int*)(wsb + B_FLAGC);
    int*   tokIdx  = (int*)(wsb + B_TIDX);
    int*   flist   = (int*)(wsb + B_FLIST);
    float* dw      = (float*)(wsb + B_DW);

    // zero-init (d_out / d_ws are poisoned with 0xAA before every call).
    hipMemsetAsync(counts, 0, KEMB * sizeof(float), stream);
    hipMemsetAsync(nptr, 0, 8, stream);                                    // n + flagCount
    hipMemsetAsync(dw, 0, (size_t)KEMB * DDIM * sizeof(float), stream);

    splitA_kernel<<<(NTOK * 32) / 256, 256, 0, stream>>>(xg, Ahat);
    splitB_kernel<<<(KEMB * 32) / 256, 256, 0, stream>>>(cbg, Bhat, ce);
    gemm_argmin_kernel<<<dim3(NTOK / 128, KEMB / 128), 256, 0, stream>>>(Ahat, Bhat, ce, part);
    argmin_reduce_kernel<<<NTOK / 4, 256, 0, stream>>>(part, tokIdx, flist, flagCnt);
    refine_kernel<<<256, 256, 0, stream>>>(xg, cbg, tokIdx, flist, flagCnt);
    scatter_kernel<<<NTOK, 256, 0, stream>>>(xg, cbg, tokIdx, quant, enc, dw, counts);
    cs_kernel<<<KEMB / 256, 256, 0, stream>>>(ema_cs, counts, cs_pre, nptr);
    epi_kernel<<<(KEMB * DDIM) / 256, 256, 0, stream>>>(ema_w, dw, cs_pre, nptr,
                                                        new_cb, new_w, cs_out);
}